// Round 1
// baseline (835.131 us; speedup 1.0000x reference)
//
#include <hip/hip_runtime.h>
#include <hip/hip_bf16.h>

#define BB 16
#define NN 512
#define DIN 256
#define DOUT 256
#define HH 8
#define HD 32
#define EE 131072
#define MM (BB*NN)    // 8192 rows
#define BH (BB*HH)    // 128
#define ROWS (BH*NN)  // 65536 (b,h,q) rows

__device__ __forceinline__ unsigned short f2bf(float f) {
    unsigned int u = __float_as_uint(f);
    unsigned int r = (u + 0x7fffu + ((u >> 16) & 1u)) >> 16;
    return (unsigned short)r;
}

// ---------------- mask build: bitmask[b][r] = 512 bits over dst cols ----------------
__global__ void mask_build(const int* __restrict__ src, const int* __restrict__ dst,
                           unsigned int* __restrict__ mask) {
    int t = blockIdx.x * 256 + threadIdx.x;
    if (t < EE) {
        int s = src[t], d = dst[t];
        int b = s / NN, r = s % NN, c = d % NN;
        atomicOr(&mask[(b * NN + r) * 16 + (c >> 5)], 1u << (c & 31));
    }
    if (t < MM) {
        int b = t / NN, r = t % NN;
        atomicOr(&mask[(b * NN + r) * 16 + (r >> 5)], 1u << (r & 31));
    }
}

// ---------------- fused QKV projection: 64x64 tile fp32 GEMM ----------------
// z = 0/1/2 -> q (fp32), k (fp32), v (bf16); output layout (B,H,N,HD)
__global__ __launch_bounds__(256) void proj_qkv(
    const float* __restrict__ hin,
    const float* __restrict__ Wq, const float* __restrict__ bq,
    const float* __restrict__ Wk, const float* __restrict__ bk,
    const float* __restrict__ Wv, const float* __restrict__ bv,
    float* __restrict__ qbuf, float* __restrict__ kbuf, unsigned short* __restrict__ vbuf) {
    __shared__ float As[16][68];  // [kk][row], padded
    __shared__ float Bs[16][68];  // [kk][col], padded
    const int t = threadIdx.x;
    const int m0 = blockIdx.x * 64;
    const int n0 = blockIdx.y * 64;
    const int z = blockIdx.z;
    const float* W    = (z == 0) ? Wq : (z == 1) ? Wk : Wv;
    const float* bias = (z == 0) ? bq : (z == 1) ? bk : bv;
    const int tx = t & 15, ty = t >> 4;
    float c[4][4] = {};
    for (int k0 = 0; k0 < DIN; k0 += 16) {
        {
            int r = t >> 2, kq = (t & 3) * 4;
            float4 a = *(const float4*)&hin[(size_t)(m0 + r) * DIN + k0 + kq];
            As[kq + 0][r] = a.x; As[kq + 1][r] = a.y; As[kq + 2][r] = a.z; As[kq + 3][r] = a.w;
            int kk = t >> 4, cq = (t & 15) * 4;
            float4 w = *(const float4*)&W[(size_t)(k0 + kk) * DOUT + n0 + cq];
            *(float4*)&Bs[kk][cq] = w;
        }
        __syncthreads();
        #pragma unroll
        for (int kk = 0; kk < 16; ++kk) {
            float4 a4 = *(const float4*)&As[kk][ty * 4];
            float4 b4 = *(const float4*)&Bs[kk][tx * 4];
            float av[4] = {a4.x, a4.y, a4.z, a4.w};
            float bv4[4] = {b4.x, b4.y, b4.z, b4.w};
            #pragma unroll
            for (int i = 0; i < 4; ++i)
                #pragma unroll
                for (int j = 0; j < 4; ++j)
                    c[i][j] += av[i] * bv4[j];
        }
        __syncthreads();
    }
    #pragma unroll
    for (int i = 0; i < 4; ++i) {
        int ii = m0 + ty * 4 + i;
        int b = ii >> 9, n = ii & 511;
        #pragma unroll
        for (int j = 0; j < 4; ++j) {
            int jj = n0 + tx * 4 + j;
            float val = c[i][j] + bias[jj];
            int hh = jj >> 5, hd = jj & 31;
            size_t idx = (((size_t)(b * HH + hh)) * NN + n) * HD + hd;
            if (z == 0)      qbuf[idx] = val;
            else if (z == 1) kbuf[idx] = val;
            else             vbuf[idx] = f2bf(val);
        }
    }
}

// ---------------- attention over one key-half (256 keys), split-softmax partials ----------------
__global__ __launch_bounds__(256) void attn_half(
    const float* __restrict__ qbuf, const float* __restrict__ kbuf,
    const unsigned short* __restrict__ vbuf, const unsigned int* __restrict__ mask,
    float* __restrict__ part) {
    __shared__ float Ks[256 * 33];          // 33792 B, stride 33 -> conflict-free
    __shared__ unsigned short Vs[256 * 34]; // 17408 B, stride 34 (68 B rows)
    __shared__ float Qs[64 * 33];           // 8448 B
    const int t = threadIdx.x;
    const int bh = blockIdx.x;
    const int q0 = blockIdx.y * 64;
    const int half = blockIdx.z;
    const int b = bh >> 3;

    // stage K half: 256 keys x 32 dims fp32
    const float* kg = kbuf + ((size_t)bh * NN + half * 256) * HD;
    #pragma unroll
    for (int it = 0; it < 8; ++it) {
        int f = t + 256 * it;        // float4 id, 2048 total
        int key = f >> 3, dq = (f & 7) * 4;
        float4 kv = *(const float4*)&kg[(size_t)f * 4];
        Ks[key * 33 + dq + 0] = kv.x;
        Ks[key * 33 + dq + 1] = kv.y;
        Ks[key * 33 + dq + 2] = kv.z;
        Ks[key * 33 + dq + 3] = kv.w;
    }
    // stage V half: 256 keys x 32 dims bf16
    const unsigned short* vg = vbuf + ((size_t)bh * NN + half * 256) * HD;
    #pragma unroll
    for (int it = 0; it < 4; ++it) {
        int f = t + 256 * it;        // uint4 id (8 bf16), 1024 total
        int key = f >> 2, dq = (f & 3) * 8;
        uint4 vv = *(const uint4*)&vg[(size_t)f * 8];
        unsigned int* vp = (unsigned int*)&Vs[key * 34 + dq];
        vp[0] = vv.x; vp[1] = vv.y; vp[2] = vv.z; vp[3] = vv.w;
    }
    // stage Q tile: 64 rows x 32 dims fp32
    const float* qg = qbuf + ((size_t)bh * NN + q0) * HD;
    #pragma unroll
    for (int it = 0; it < 2; ++it) {
        int f = t + 256 * it;        // float4 id, 512 total
        int r = f >> 3, dq = (f & 7) * 4;
        float4 qv = *(const float4*)&qg[(size_t)f * 4];
        Qs[r * 33 + dq + 0] = qv.x;
        Qs[r * 33 + dq + 1] = qv.y;
        Qs[r * 33 + dq + 2] = qv.z;
        Qs[r * 33 + dq + 3] = qv.w;
    }
    __syncthreads();

    const int wave = t >> 6, lane = t & 63;
    const float scale = 0.17677669529663687f;  // 1/sqrt(32)

    for (int ir = 0; ir < 16; ++ir) {
        int r = wave * 16 + ir;
        int qrow = q0 + r;
        float qreg[32];
        #pragma unroll
        for (int d = 0; d < 32; ++d) qreg[d] = Qs[r * 33 + d];

        // scores: 4 keys per lane
        float s[4];
        const unsigned int* mrow = mask + ((size_t)(b * NN + qrow)) * 16 + half * 8;
        #pragma unroll
        for (int j = 0; j < 4; ++j) {
            int k = lane + 64 * j;
            float acc = 0.f;
            #pragma unroll
            for (int d = 0; d < 32; ++d) acc += qreg[d] * Ks[k * 33 + d];
            unsigned int mw = mrow[k >> 5];
            s[j] = ((mw >> (k & 31)) & 1u) ? acc * scale : -1e9f;
        }
        // wave softmax (within this half)
        float m = fmaxf(fmaxf(s[0], s[1]), fmaxf(s[2], s[3]));
        #pragma unroll
        for (int o = 1; o < 64; o <<= 1) m = fmaxf(m, __shfl_xor(m, o));
        float e[4], l = 0.f;
        #pragma unroll
        for (int j = 0; j < 4; ++j) { e[j] = __expf(s[j] - m); l += e[j]; }
        #pragma unroll
        for (int o = 1; o < 64; o <<= 1) l += __shfl_xor(l, o);
        // PV partial
        float acc[32];
        #pragma unroll
        for (int d = 0; d < 32; ++d) acc[d] = 0.f;
        #pragma unroll
        for (int j = 0; j < 4; ++j) {
            int k = lane + 64 * j;
            const unsigned int* vrow = (const unsigned int*)&Vs[k * 34];
            #pragma unroll
            for (int dp = 0; dp < 16; ++dp) {
                unsigned int w2 = vrow[dp];
                float vlo = __uint_as_float(w2 << 16);
                float vhi = __uint_as_float(w2 & 0xffff0000u);
                acc[2 * dp]     += e[j] * vlo;
                acc[2 * dp + 1] += e[j] * vhi;
            }
        }
        // reduce across lanes: butterfly within 32-lane halves, then pair-join
        #pragma unroll
        for (int o = 1; o < 32; o <<= 1)
            #pragma unroll
            for (int d = 0; d < 32; ++d) acc[d] += __shfl_xor(acc[d], o);
        int dsel = lane & 31;
        float outv = acc[0];
        #pragma unroll
        for (int d = 1; d < 32; ++d) outv = (dsel == d) ? acc[d] : outv;
        outv += __shfl_xor(outv, 32);

        float* p = part + ((size_t)half * ROWS + (size_t)bh * NN + qrow) * 36;
        if (lane < 32)       p[lane] = outv;
        else if (lane == 32) p[32] = m;
        else if (lane == 33) p[33] = l;
    }
}

// ---------------- combine the two key-half partials -> attn (B*N, 256) ----------------
__global__ void combine(const float* __restrict__ part, float* __restrict__ attn) {
    int t = blockIdx.x * 256 + threadIdx.x;  // ROWS*32 threads
    int row = t >> 5, d = t & 31;
    const float* p0 = part + (size_t)row * 36;
    const float* p1 = part + ((size_t)ROWS + row) * 36;
    float m0 = p0[32], l0 = p0[33];
    float m1 = p1[32], l1 = p1[33];
    float M = fmaxf(m0, m1);
    float e0 = __expf(m0 - M), e1 = __expf(m1 - M);
    float denom = e0 * l0 + e1 * l1;
    float v = (e0 * p0[d] + e1 * p1[d]) / denom;
    int b = row >> 12;
    int hh = (row >> 9) & 7;
    int q = row & 511;
    attn[((size_t)(b * NN + q)) * DOUT + hh * HD + d] = v;
}

// ---------------- output projection ----------------
__global__ __launch_bounds__(256) void proj_out(
    const float* __restrict__ A, const float* __restrict__ W,
    const float* __restrict__ bias, float* __restrict__ out) {
    __shared__ float As[16][68];
    __shared__ float Bs[16][68];
    const int t = threadIdx.x;
    const int m0 = blockIdx.x * 64;
    const int n0 = blockIdx.y * 64;
    const int tx = t & 15, ty = t >> 4;
    float c[4][4] = {};
    for (int k0 = 0; k0 < DOUT; k0 += 16) {
        {
            int r = t >> 2, kq = (t & 3) * 4;
            float4 a = *(const float4*)&A[(size_t)(m0 + r) * DOUT + k0 + kq];
            As[kq + 0][r] = a.x; As[kq + 1][r] = a.y; As[kq + 2][r] = a.z; As[kq + 3][r] = a.w;
            int kk = t >> 4, cq = (t & 15) * 4;
            float4 w = *(const float4*)&W[(size_t)(k0 + kk) * DOUT + n0 + cq];
            *(float4*)&Bs[kk][cq] = w;
        }
        __syncthreads();
        #pragma unroll
        for (int kk = 0; kk < 16; ++kk) {
            float4 a4 = *(const float4*)&As[kk][ty * 4];
            float4 b4 = *(const float4*)&Bs[kk][tx * 4];
            float av[4] = {a4.x, a4.y, a4.z, a4.w};
            float bv4[4] = {b4.x, b4.y, b4.z, b4.w};
            #pragma unroll
            for (int i = 0; i < 4; ++i)
                #pragma unroll
                for (int j = 0; j < 4; ++j)
                    c[i][j] += av[i] * bv4[j];
        }
        __syncthreads();
    }
    #pragma unroll
    for (int i = 0; i < 4; ++i) {
        int ii = m0 + ty * 4 + i;
        #pragma unroll
        for (int j = 0; j < 4; ++j) {
            int jj = n0 + tx * 4 + j;
            out[(size_t)ii * DOUT + jj] = c[i][j] + bias[jj];
        }
    }
}

extern "C" void kernel_launch(void* const* d_in, const int* in_sizes, int n_in,
                              void* d_out, int out_size, void* d_ws, size_t ws_size,
                              hipStream_t stream) {
    const float* hin = (const float*)d_in[0];
    const int* src   = (const int*)d_in[1];
    const int* dst   = (const int*)d_in[2];
    const float* Wq  = (const float*)d_in[3];
    const float* bq  = (const float*)d_in[4];
    const float* Wk  = (const float*)d_in[5];
    const float* bk  = (const float*)d_in[6];
    const float* Wv  = (const float*)d_in[7];
    const float* bv  = (const float*)d_in[8];
    const float* Wo  = (const float*)d_in[9];
    const float* bo  = (const float*)d_in[10];

    char* ws = (char*)d_ws;
    unsigned int* mask   = (unsigned int*)ws;                       // 524288 B
    float* qbuf          = (float*)(ws + 524288);                   // 8 MB
    float* kbuf          = (float*)(ws + 524288 + 8388608);         // 8 MB
    unsigned short* vbuf = (unsigned short*)(ws + 524288 + 16777216); // 4 MB
    float* part          = (float*)(ws + 524288 + 16777216 + 4194304); // 18 MB
    float* attn          = (float*)(ws + 524288 + 16777216 + 4194304 + 18874368); // 8 MB
    float* out = (float*)d_out;

    hipMemsetAsync(mask, 0, 524288, stream);
    mask_build<<<(EE + 255) / 256, 256, 0, stream>>>(src, dst, mask);
    proj_qkv<<<dim3(MM / 64, DOUT / 64, 3), 256, 0, stream>>>(hin, Wq, bq, Wk, bk, Wv, bv,
                                                              qbuf, kbuf, vbuf);
    attn_half<<<dim3(BH, NN / 64, 2), 256, 0, stream>>>(qbuf, kbuf, vbuf, mask, part);
    combine<<<(ROWS * 32) / 256, 256, 0, stream>>>(part, attn);
    proj_out<<<dim3(MM / 64, DOUT / 64), 256, 0, stream>>>(attn, Wo, bo, out);
}

// Round 2
// 102.630 us; speedup vs baseline: 8.1373x; 8.1373x over previous
//
#include <hip/hip_runtime.h>
#include <hip/hip_bf16.h>

#define BB 16
#define NN 512
#define DIN 256
#define DOUT 256
#define HH 8
#define HD 32
#define EE 131072
#define MM (BB*NN)    // 8192 rows
#define BH (BB*HH)    // 128

typedef unsigned short ushort_t;
typedef __attribute__((ext_vector_type(8))) short bf16x8;
typedef __attribute__((ext_vector_type(4))) float f32x4;

__device__ __forceinline__ unsigned short f2bf(float f) {
    unsigned int u = __float_as_uint(f);
    unsigned int r = (u + 0x7fffu + ((u >> 16) & 1u)) >> 16;
    return (unsigned short)r;
}

// ---------------- mask build: transposed bitmask maskT[b][word][row] ----------------
__global__ void mask_build(const int* __restrict__ src, const int* __restrict__ dst,
                           unsigned int* __restrict__ maskT) {
    int t = blockIdx.x * 256 + threadIdx.x;
    if (t < EE) {
        int s = src[t], d = dst[t];
        int b = s / NN, r = s % NN, c = d % NN;
        atomicOr(&maskT[((size_t)(b * 16) + (c >> 5)) * NN + r], 1u << (c & 31));
    }
    if (t < MM) {
        int b = t / NN, r = t % NN;
        atomicOr(&maskT[((size_t)(b * 16) + (r >> 5)) * NN + r], 1u << (r & 31));
    }
}

// ---------------- fused QKV projection: 64x64 tile fp32 GEMM -> bf16 outputs ----------------
// z = 0/1/2 -> q (B,H,N,HD), k (B,H,N,HD), v transposed (B,H,HD,N)
__global__ __launch_bounds__(256) void proj_qkv(
    const float* __restrict__ hin,
    const float* __restrict__ Wq, const float* __restrict__ bq,
    const float* __restrict__ Wk, const float* __restrict__ bk,
    const float* __restrict__ Wv, const float* __restrict__ bv,
    ushort_t* __restrict__ qb, ushort_t* __restrict__ kb, ushort_t* __restrict__ vT) {
    __shared__ float As[16][68];
    __shared__ float Bs[16][68];
    const int t = threadIdx.x;
    const int m0 = blockIdx.x * 64;
    const int n0 = blockIdx.y * 64;
    const int z = blockIdx.z;
    const float* W    = (z == 0) ? Wq : (z == 1) ? Wk : Wv;
    const float* bias = (z == 0) ? bq : (z == 1) ? bk : bv;
    const int tx = t & 15, ty = t >> 4;
    float c[4][4] = {};
    for (int k0 = 0; k0 < DIN; k0 += 16) {
        {
            int r = t >> 2, kq = (t & 3) * 4;
            float4 a = *(const float4*)&hin[(size_t)(m0 + r) * DIN + k0 + kq];
            As[kq + 0][r] = a.x; As[kq + 1][r] = a.y; As[kq + 2][r] = a.z; As[kq + 3][r] = a.w;
            int kk = t >> 4, cq = (t & 15) * 4;
            float4 w = *(const float4*)&W[(size_t)(k0 + kk) * DOUT + n0 + cq];
            *(float4*)&Bs[kk][cq] = w;
        }
        __syncthreads();
        #pragma unroll
        for (int kk = 0; kk < 16; ++kk) {
            float4 a4 = *(const float4*)&As[kk][ty * 4];
            float4 b4 = *(const float4*)&Bs[kk][tx * 4];
            float av[4] = {a4.x, a4.y, a4.z, a4.w};
            float bv4[4] = {b4.x, b4.y, b4.z, b4.w};
            #pragma unroll
            for (int i = 0; i < 4; ++i)
                #pragma unroll
                for (int j = 0; j < 4; ++j)
                    c[i][j] += av[i] * bv4[j];
        }
        __syncthreads();
    }
    #pragma unroll
    for (int i = 0; i < 4; ++i) {
        int ii = m0 + ty * 4 + i;
        int b = ii >> 9, n = ii & 511;
        #pragma unroll
        for (int j = 0; j < 4; ++j) {
            int jj = n0 + tx * 4 + j;
            float val = c[i][j] + bias[jj];
            int hh = jj >> 5, hd = jj & 31;
            unsigned short bv16 = f2bf(val);
            if (z == 0)      qb[(((size_t)(b * HH + hh)) * NN + n) * HD + hd] = bv16;
            else if (z == 1) kb[(((size_t)(b * HH + hh)) * NN + n) * HD + hd] = bv16;
            else             vT[(((size_t)(b * HH + hh)) * HD + hd) * NN + n] = bv16;
        }
    }
}

// ---------------- MFMA flash attention: one block = 64 q-rows of one (b,h) ----------------
__global__ __launch_bounds__(256, 2) void attn_mfma(
    const ushort_t* __restrict__ qb, const ushort_t* __restrict__ kb,
    const ushort_t* __restrict__ vT, const unsigned int* __restrict__ maskT,
    float* __restrict__ attnb) {
    __shared__ ushort_t Ks[512 * 40];   // [key][40], 80B rows, 16B-aligned slots, ~2-way banks
    __shared__ ushort_t Vt[32 * 520];   // [dim][520], 1040B rows
    __shared__ ushort_t Ps[4][640];     // per-wave P scratch [16][40]

    const int t = threadIdx.x;
    const int bh = blockIdx.x;
    const int q0 = blockIdx.y * 64;
    const int b = bh >> 3, h = bh & 7;
    const int wid = t >> 6, lane = t & 63;
    const int g = lane >> 4, c = lane & 15;

    // stage K (512x32 bf16, row-major, padded stride 40)
    const ushort_t* kg = kb + (size_t)bh * NN * HD;
    #pragma unroll
    for (int it = 0; it < 8; ++it) {
        int f = t + 256 * it;           // 2048 chunks of 8 bf16
        int key = f >> 2, dq = (f & 3) * 8;
        uint4 kv = *(const uint4*)(kg + (size_t)f * 8);
        *(uint4*)&Ks[key * 40 + dq] = kv;
    }
    // stage V^T (32x512 bf16, padded stride 520)
    const ushort_t* vg = vT + (size_t)bh * HD * NN;
    #pragma unroll
    for (int it = 0; it < 8; ++it) {
        int f = t + 256 * it;           // 2048 chunks of 8 bf16
        int dim = f >> 6, ko = (f & 63) * 8;
        uint4 vv = *(const uint4*)(vg + (size_t)f * 8);
        *(uint4*)&Vt[dim * 520 + ko] = vv;
    }
    // Q fragment: A[row=lane&15][k=8g..8g+7], rows q0+wid*16+c
    bf16x8 qa = *(const bf16x8*)(qb + ((size_t)bh * NN + q0 + wid * 16 + c) * HD + 8 * g);
    __syncthreads();

    const f32x4 zf = {0.f, 0.f, 0.f, 0.f};
    f32x4 acc0 = zf, acc1 = zf;
    float lsum[4] = {0.f, 0.f, 0.f, 0.f};
    ushort_t* Pw = &Ps[wid][0];
    const float SCALE = 0.17677669529663687f;  // 1/sqrt(32)
    const size_t mbase = (size_t)b * 8192 + q0 + wid * 16 + 4 * g;

    #pragma unroll 4
    for (int kt = 0; kt < 16; ++kt) {
        uint4 mw = *(const uint4*)(maskT + mbase + (size_t)kt * 512);  // words rows 4g..4g+3
        bf16x8 kb0 = *(const bf16x8*)&Ks[(kt * 32 + c) * 40 + 8 * g];
        bf16x8 kb1 = *(const bf16x8*)&Ks[(kt * 32 + 16 + c) * 40 + 8 * g];
        f32x4 s0 = __builtin_amdgcn_mfma_f32_16x16x32_bf16(qa, kb0, zf, 0, 0, 0);
        f32x4 s1 = __builtin_amdgcn_mfma_f32_16x16x32_bf16(qa, kb1, zf, 0, 0, 0);
        const unsigned int* mwp = (const unsigned int*)&mw;
        #pragma unroll
        for (int r = 0; r < 4; ++r) {
            unsigned int w = mwp[r];
            // fixed-offset softmax: logits bounded << 16, final /l renormalizes
            float p0 = ((w >> c) & 1u)        ? __expf(fmaf(s0[r], SCALE, -16.0f)) : 0.f;
            float p1 = ((w >> (16 + c)) & 1u) ? __expf(fmaf(s1[r], SCALE, -16.0f)) : 0.f;
            lsum[r] += p0 + p1;
            Pw[(4 * g + r) * 40 + c]      = f2bf(p0);
            Pw[(4 * g + r) * 40 + 16 + c] = f2bf(p1);
        }
        bf16x8 pa  = *(const bf16x8*)&Pw[c * 40 + 8 * g];
        bf16x8 vb0 = *(const bf16x8*)&Vt[c * 520 + kt * 32 + 8 * g];
        bf16x8 vb1 = *(const bf16x8*)&Vt[(16 + c) * 520 + kt * 32 + 8 * g];
        acc0 = __builtin_amdgcn_mfma_f32_16x16x32_bf16(pa, vb0, acc0, 0, 0, 0);
        acc1 = __builtin_amdgcn_mfma_f32_16x16x32_bf16(pa, vb1, acc1, 0, 0, 0);
    }

    // reduce l across the 16 lanes of each group (rows 4g..4g+3)
    #pragma unroll
    for (int r = 0; r < 4; ++r) {
        float l = lsum[r];
        l += __shfl_xor(l, 1);
        l += __shfl_xor(l, 2);
        l += __shfl_xor(l, 4);
        l += __shfl_xor(l, 8);
        lsum[r] = l;
    }
    #pragma unroll
    for (int r = 0; r < 4; ++r) {
        float rl = 1.0f / lsum[r];
        float* orow = attnb + ((size_t)(b * NN + q0 + wid * 16 + 4 * g + r)) * DOUT + h * HD;
        orow[c]      = acc0[r] * rl;
        orow[16 + c] = acc1[r] * rl;
    }
}

// ---------------- output projection (fp32) ----------------
__global__ __launch_bounds__(256) void proj_out(
    const float* __restrict__ A, const float* __restrict__ W,
    const float* __restrict__ bias, float* __restrict__ out) {
    __shared__ float As[16][68];
    __shared__ float Bs[16][68];
    const int t = threadIdx.x;
    const int m0 = blockIdx.x * 64;
    const int n0 = blockIdx.y * 64;
    const int tx = t & 15, ty = t >> 4;
    float c[4][4] = {};
    for (int k0 = 0; k0 < DOUT; k0 += 16) {
        {
            int r = t >> 2, kq = (t & 3) * 4;
            float4 a = *(const float4*)&A[(size_t)(m0 + r) * DOUT + k0 + kq];
            As[kq + 0][r] = a.x; As[kq + 1][r] = a.y; As[kq + 2][r] = a.z; As[kq + 3][r] = a.w;
            int kk = t >> 4, cq = (t & 15) * 4;
            float4 w = *(const float4*)&W[(size_t)(k0 + kk) * DOUT + n0 + cq];
            *(float4*)&Bs[kk][cq] = w;
        }
        __syncthreads();
        #pragma unroll
        for (int kk = 0; kk < 16; ++kk) {
            float4 a4 = *(const float4*)&As[kk][ty * 4];
            float4 b4 = *(const float4*)&Bs[kk][tx * 4];
            float av[4] = {a4.x, a4.y, a4.z, a4.w};
            float bv4[4] = {b4.x, b4.y, b4.z, b4.w};
            #pragma unroll
            for (int i = 0; i < 4; ++i)
                #pragma unroll
                for (int j = 0; j < 4; ++j)
                    c[i][j] += av[i] * bv4[j];
        }
        __syncthreads();
    }
    #pragma unroll
    for (int i = 0; i < 4; ++i) {
        int ii = m0 + ty * 4 + i;
        #pragma unroll
        for (int j = 0; j < 4; ++j) {
            int jj = n0 + tx * 4 + j;
            out[(size_t)ii * DOUT + jj] = c[i][j] + bias[jj];
        }
    }
}

extern "C" void kernel_launch(void* const* d_in, const int* in_sizes, int n_in,
                              void* d_out, int out_size, void* d_ws, size_t ws_size,
                              hipStream_t stream) {
    const float* hin = (const float*)d_in[0];
    const int* src   = (const int*)d_in[1];
    const int* dst   = (const int*)d_in[2];
    const float* Wq  = (const float*)d_in[3];
    const float* bq  = (const float*)d_in[4];
    const float* Wk  = (const float*)d_in[5];
    const float* bk  = (const float*)d_in[6];
    const float* Wv  = (const float*)d_in[7];
    const float* bv  = (const float*)d_in[8];
    const float* Wo  = (const float*)d_in[9];
    const float* bo  = (const float*)d_in[10];

    char* ws = (char*)d_ws;
    unsigned int* maskT = (unsigned int*)ws;                       // 512 KB
    ushort_t* qb  = (ushort_t*)(ws + 524288);                      // 4 MB
    ushort_t* kb  = (ushort_t*)(ws + 524288 + 4194304);            // 4 MB
    ushort_t* vT  = (ushort_t*)(ws + 524288 + 2 * 4194304);        // 4 MB
    float* attnb  = (float*)(ws + 524288 + 3 * 4194304);           // 8 MB
    float* out = (float*)d_out;

    hipMemsetAsync(maskT, 0, 524288, stream);
    mask_build<<<(EE + 255) / 256, 256, 0, stream>>>(src, dst, maskT);
    proj_qkv<<<dim3(MM / 64, DOUT / 64, 3), 256, 0, stream>>>(hin, Wq, bq, Wk, bk, Wv, bv,
                                                              qb, kb, vT);
    attn_mfma<<<dim3(BH, NN / 64), 256, 0, stream>>>(qb, kb, vT, maskT, attnb);
    proj_out<<<dim3(MM / 64, DOUT / 64), 256, 0, stream>>>(attnb, Wo, bo, out);
}

// Round 3
// 62.274 us; speedup vs baseline: 13.4106x; 1.6480x over previous
//
#include <hip/hip_runtime.h>
#include <hip/hip_bf16.h>

#define BB 16
#define NN 512
#define DIN 256
#define DOUT 256
#define HH 8
#define HD 32
#define EE 131072
#define MM (BB*NN)    // 8192 rows
#define BH (BB*HH)    // 128

typedef unsigned short ushort_t;
typedef __attribute__((ext_vector_type(8))) short bf16x8;
typedef __attribute__((ext_vector_type(4))) float f32x4;

__device__ __forceinline__ unsigned short f2bf(float f) {
    unsigned int u = __float_as_uint(f);
    unsigned int r = (u + 0x7fffu + ((u >> 16) & 1u)) >> 16;
    return (unsigned short)r;
}

// ---------------- mask build: transposed bitmask maskT[b][word][row] ----------------
__global__ void mask_build(const int* __restrict__ src, const int* __restrict__ dst,
                           unsigned int* __restrict__ maskT) {
    int t = blockIdx.x * 256 + threadIdx.x;
    if (t < EE) {
        int s = src[t], d = dst[t];
        int b = s / NN, r = s % NN, c = d % NN;
        atomicOr(&maskT[((size_t)(b * 16) + (c >> 5)) * NN + r], 1u << (c & 31));
    }
    if (t < MM) {
        int b = t / NN, r = t % NN;
        atomicOr(&maskT[((size_t)(b * 16) + (r >> 5)) * NN + r], 1u << (r & 31));
    }
}

// ---------------- h fp32 -> bf16 ----------------
__global__ __launch_bounds__(256) void h2bf(const float* __restrict__ h,
                                            ushort_t* __restrict__ hb) {
    int chunk = blockIdx.x * 256 + threadIdx.x;   // 262144 chunks of 8
    float4 a = *(const float4*)(h + (size_t)chunk * 8);
    float4 b = *(const float4*)(h + (size_t)chunk * 8 + 4);
    ushort_t o[8] = {f2bf(a.x), f2bf(a.y), f2bf(a.z), f2bf(a.w),
                     f2bf(b.x), f2bf(b.y), f2bf(b.z), f2bf(b.w)};
    *(uint4*)(hb + (size_t)chunk * 8) = *(const uint4*)o;
}

// ---------------- weight transpose+convert: Wt[768][256] = [Wq^T;Wk^T;Wv^T], Wot[256][256] = Wo^T ----------------
__global__ __launch_bounds__(256) void wprep(
    const float* __restrict__ Wq, const float* __restrict__ Wk,
    const float* __restrict__ Wv, const float* __restrict__ Wo,
    ushort_t* __restrict__ Wt, ushort_t* __restrict__ Wot) {
    int tg = blockIdx.x * 256 + threadIdx.x;      // 262144 = 1024 rows x 256 cols
    int n = tg >> 8, k = tg & 255;
    if (n < 768) {
        const float* W = (n < 256) ? Wq : (n < 512) ? Wk : Wv;
        Wt[(size_t)n * 256 + k] = f2bf(W[(size_t)k * 256 + (n & 255)]);
    } else {
        int nn = n - 768;
        Wot[(size_t)nn * 256 + k] = f2bf(Wo[(size_t)k * 256 + nn]);
    }
}

// ---------------- bf16 MFMA GEMM: C[M x N] = A[M x 256] * Bt[N x 256]^T + bias ----------------
// MODE 0: N=768 fused QKV -> scatter to qb/kb (B,H,N,HD) and vT (B,H,HD,N), bf16
// MODE 1: N=256 output projection -> fp32 row-major out
template<int MODE>
__global__ __launch_bounds__(256) void gemm_mfma(
    const ushort_t* __restrict__ A, const ushort_t* __restrict__ Bt,
    const float* __restrict__ b0, const float* __restrict__ b1, const float* __restrict__ b2,
    ushort_t* __restrict__ qb, ushort_t* __restrict__ kb, ushort_t* __restrict__ vT,
    float* __restrict__ fout) {
    __shared__ ushort_t As[64][72];
    __shared__ ushort_t Bs[64][72];
    const int t = threadIdx.x;
    const int m0 = blockIdx.x * 64, n0 = blockIdx.y * 64;
    const int wid = t >> 6, lane = t & 63, g = lane >> 4, c = lane & 15;
    const int wr = wid >> 1, wc = wid & 1;

    f32x4 acc00 = {0.f,0.f,0.f,0.f}, acc01 = acc00, acc10 = acc00, acc11 = acc00;

    for (int k0 = 0; k0 < 256; k0 += 64) {
        #pragma unroll
        for (int i = 0; i < 2; ++i) {
            int f = t + i * 256;
            int row = f >> 3, c16 = f & 7;
            *(uint4*)&As[row][c16 * 8] = *(const uint4*)(A  + (size_t)(m0 + row) * 256 + k0 + c16 * 8);
            *(uint4*)&Bs[row][c16 * 8] = *(const uint4*)(Bt + (size_t)(n0 + row) * 256 + k0 + c16 * 8);
        }
        __syncthreads();
        #pragma unroll
        for (int kk = 0; kk < 2; ++kk) {
            bf16x8 a0 = *(const bf16x8*)&As[wr * 32 + c][kk * 32 + 8 * g];
            bf16x8 a1 = *(const bf16x8*)&As[wr * 32 + 16 + c][kk * 32 + 8 * g];
            bf16x8 bb0 = *(const bf16x8*)&Bs[wc * 32 + c][kk * 32 + 8 * g];
            bf16x8 bb1 = *(const bf16x8*)&Bs[wc * 32 + 16 + c][kk * 32 + 8 * g];
            acc00 = __builtin_amdgcn_mfma_f32_16x16x32_bf16(a0, bb0, acc00, 0, 0, 0);
            acc01 = __builtin_amdgcn_mfma_f32_16x16x32_bf16(a0, bb1, acc01, 0, 0, 0);
            acc10 = __builtin_amdgcn_mfma_f32_16x16x32_bf16(a1, bb0, acc10, 0, 0, 0);
            acc11 = __builtin_amdgcn_mfma_f32_16x16x32_bf16(a1, bb1, acc11, 0, 0, 0);
        }
        __syncthreads();
    }

    // epilogue: value (mi,nj,r) -> row m0+wr*32+mi*16+4g+r, col n0+wc*32+nj*16+c
    #pragma unroll
    for (int mi = 0; mi < 2; ++mi) {
        #pragma unroll
        for (int nj = 0; nj < 2; ++nj) {
            const f32x4 av = (mi == 0) ? (nj == 0 ? acc00 : acc01) : (nj == 0 ? acc10 : acc11);
            const int m_base = m0 + wr * 32 + mi * 16 + 4 * g;
            const int n_base = n0 + wc * 32 + nj * 16;
            if (MODE == 1) {
                const float bias = b0[n_base + c];
                #pragma unroll
                for (int r = 0; r < 4; ++r)
                    fout[(size_t)(m_base + r) * 256 + n_base + c] = av[r] + bias;
            } else {
                const int z = n_base >> 8, nn = n_base & 255;
                const int hh = nn >> 5, hd = (nn & 31) + c;
                const float* bp = (z == 0) ? b0 : (z == 1) ? b1 : b2;
                const float bias = bp[nn + c];
                const int b = m_base >> 9, nrow = m_base & 511;
                if (z == 2) {
                    #pragma unroll
                    for (int r = 0; r < 4; ++r)
                        vT[(((size_t)(b * 8 + hh)) * 32 + hd) * 512 + nrow + r] = f2bf(av[r] + bias);
                } else {
                    ushort_t* dst = (z == 0) ? qb : kb;
                    #pragma unroll
                    for (int r = 0; r < 4; ++r)
                        dst[(((size_t)(b * 8 + hh)) * 512 + nrow + r) * 32 + hd] = f2bf(av[r] + bias);
                }
            }
        }
    }
}

// ---------------- MFMA flash attention: one block = 64 q-rows of one (b,h) ----------------
__global__ __launch_bounds__(256, 2) void attn_mfma(
    const ushort_t* __restrict__ qb, const ushort_t* __restrict__ kb,
    const ushort_t* __restrict__ vT, const unsigned int* __restrict__ maskT,
    ushort_t* __restrict__ attnb) {
    __shared__ ushort_t Ks[512 * 40];
    __shared__ ushort_t Vt[32 * 520];
    __shared__ ushort_t Ps[4][640];

    const int t = threadIdx.x;
    const int bh = blockIdx.x;
    const int q0 = blockIdx.y * 64;
    const int b = bh >> 3, h = bh & 7;
    const int wid = t >> 6, lane = t & 63;
    const int g = lane >> 4, c = lane & 15;

    const ushort_t* kg = kb + (size_t)bh * NN * HD;
    #pragma unroll
    for (int it = 0; it < 8; ++it) {
        int f = t + 256 * it;
        int key = f >> 2, dq = (f & 3) * 8;
        uint4 kv = *(const uint4*)(kg + (size_t)f * 8);
        *(uint4*)&Ks[key * 40 + dq] = kv;
    }
    const ushort_t* vg = vT + (size_t)bh * HD * NN;
    #pragma unroll
    for (int it = 0; it < 8; ++it) {
        int f = t + 256 * it;
        int dim = f >> 6, ko = (f & 63) * 8;
        uint4 vv = *(const uint4*)(vg + (size_t)f * 8);
        *(uint4*)&Vt[dim * 520 + ko] = vv;
    }
    bf16x8 qa = *(const bf16x8*)(qb + ((size_t)bh * NN + q0 + wid * 16 + c) * HD + 8 * g);
    __syncthreads();

    const f32x4 zf = {0.f, 0.f, 0.f, 0.f};
    f32x4 acc0 = zf, acc1 = zf;
    float lsum[4] = {0.f, 0.f, 0.f, 0.f};
    ushort_t* Pw = &Ps[wid][0];
    const float SCALE = 0.17677669529663687f;
    const size_t mbase = (size_t)b * 8192 + q0 + wid * 16 + 4 * g;

    #pragma unroll 4
    for (int kt = 0; kt < 16; ++kt) {
        uint4 mw = *(const uint4*)(maskT + mbase + (size_t)kt * 512);
        bf16x8 kb0 = *(const bf16x8*)&Ks[(kt * 32 + c) * 40 + 8 * g];
        bf16x8 kb1 = *(const bf16x8*)&Ks[(kt * 32 + 16 + c) * 40 + 8 * g];
        f32x4 s0 = __builtin_amdgcn_mfma_f32_16x16x32_bf16(qa, kb0, zf, 0, 0, 0);
        f32x4 s1 = __builtin_amdgcn_mfma_f32_16x16x32_bf16(qa, kb1, zf, 0, 0, 0);
        const unsigned int* mwp = (const unsigned int*)&mw;
        #pragma unroll
        for (int r = 0; r < 4; ++r) {
            unsigned int w = mwp[r];
            float p0 = ((w >> c) & 1u)        ? __expf(fmaf(s0[r], SCALE, -16.0f)) : 0.f;
            float p1 = ((w >> (16 + c)) & 1u) ? __expf(fmaf(s1[r], SCALE, -16.0f)) : 0.f;
            lsum[r] += p0 + p1;
            Pw[(4 * g + r) * 40 + c]      = f2bf(p0);
            Pw[(4 * g + r) * 40 + 16 + c] = f2bf(p1);
        }
        bf16x8 pa  = *(const bf16x8*)&Pw[c * 40 + 8 * g];
        bf16x8 vb0 = *(const bf16x8*)&Vt[c * 520 + kt * 32 + 8 * g];
        bf16x8 vb1 = *(const bf16x8*)&Vt[(16 + c) * 520 + kt * 32 + 8 * g];
        acc0 = __builtin_amdgcn_mfma_f32_16x16x32_bf16(pa, vb0, acc0, 0, 0, 0);
        acc1 = __builtin_amdgcn_mfma_f32_16x16x32_bf16(pa, vb1, acc1, 0, 0, 0);
    }

    #pragma unroll
    for (int r = 0; r < 4; ++r) {
        float l = lsum[r];
        l += __shfl_xor(l, 1);
        l += __shfl_xor(l, 2);
        l += __shfl_xor(l, 4);
        l += __shfl_xor(l, 8);
        lsum[r] = l;
    }
    #pragma unroll
    for (int r = 0; r < 4; ++r) {
        float rl = 1.0f / lsum[r];
        ushort_t* orow = attnb + ((size_t)(b * NN + q0 + wid * 16 + 4 * g + r)) * DOUT + h * HD;
        orow[c]      = f2bf(acc0[r] * rl);
        orow[16 + c] = f2bf(acc1[r] * rl);
    }
}

extern "C" void kernel_launch(void* const* d_in, const int* in_sizes, int n_in,
                              void* d_out, int out_size, void* d_ws, size_t ws_size,
                              hipStream_t stream) {
    const float* hin = (const float*)d_in[0];
    const int* src   = (const int*)d_in[1];
    const int* dst   = (const int*)d_in[2];
    const float* Wq  = (const float*)d_in[3];
    const float* bq  = (const float*)d_in[4];
    const float* Wk  = (const float*)d_in[5];
    const float* bk  = (const float*)d_in[6];
    const float* Wv  = (const float*)d_in[7];
    const float* bv  = (const float*)d_in[8];
    const float* Wo  = (const float*)d_in[9];
    const float* bo  = (const float*)d_in[10];

    char* ws = (char*)d_ws;
    unsigned int* maskT = (unsigned int*)ws;                    // 512 KB
    ushort_t* hb    = (ushort_t*)(ws + 524288);                 // 4 MB
    ushort_t* qb    = (ushort_t*)(ws + 4718592);                // 4 MB
    ushort_t* kb    = (ushort_t*)(ws + 8912896);                // 4 MB
    ushort_t* vT    = (ushort_t*)(ws + 13107200);               // 4 MB
    ushort_t* attnb = (ushort_t*)(ws + 17301504);               // 4 MB
    ushort_t* Wt    = (ushort_t*)(ws + 21495808);               // 384 KB
    ushort_t* Wot   = (ushort_t*)(ws + 21889024);               // 128 KB
    float* out = (float*)d_out;

    hipMemsetAsync(maskT, 0, 524288, stream);
    mask_build<<<(EE + 255) / 256, 256, 0, stream>>>(src, dst, maskT);
    h2bf<<<1024, 256, 0, stream>>>(hin, hb);
    wprep<<<1024, 256, 0, stream>>>(Wq, Wk, Wv, Wo, Wt, Wot);
    gemm_mfma<0><<<dim3(MM / 64, 768 / 64), 256, 0, stream>>>(hb, Wt, bq, bk, bv,
                                                              qb, kb, vT, nullptr);
    attn_mfma<<<dim3(BH, NN / 64), 256, 0, stream>>>(qb, kb, vT, maskT, attnb);
    gemm_mfma<1><<<dim3(MM / 64, 256 / 64), 256, 0, stream>>>(attnb, Wot, bo, nullptr, nullptr,
                                                              nullptr, nullptr, nullptr, out);
}